// Round 9
// baseline (154.442 us; speedup 1.0000x reference)
//
#include <hip/hip_runtime.h>
#include <hip/hip_bf16.h>
#include <hip/hip_fp16.h>

// Problem constants (match reference)
#define CUTOFF_C    12.0f
#define CUTOFF_SR_C 2.0f
#define CUTOFF_SQ_C 144.0f
#define KEHALF_C    7.199822675975274f

#define BLK1   1024

// Fused gather+compute+scatter configs (no LUT, exact math):
// DUO : CH=20000 -> 80000 B LDS, 2 blocks/CU, nch=5 @100K, 32M visits.
// SOLO: CH=40000 -> 160000 B LDS, 1 block/CU, nch=3 (fallback if duo probe fails).
#define CH_DUO  20000
#define CH_SOLO 40000

__device__ __forceinline__ float edge_energy(float d, float qi, float qj,
                                             float di, float dj) {
    float inv_d   = __frcp_rn(d);
    float dsh     = __fsqrt_rn(fmaf(d, d, 1.0f));
    float inv_dsh = __frcp_rn(dsh);
    float x  = d * (1.0f / CUTOFF_SR_C);
    float x3 = x * x * x;
    float sw = fmaf(x3, fmaf(x, fmaf(x, -6.0f, 15.0f), -10.0f), 1.0f);
    float sw_off = (d < CUTOFF_SR_C) ? sw : 0.0f;
    float Eoq = inv_d   + fmaf(d,   (1.0f / CUTOFF_SQ_C), -(2.0f / CUTOFF_C));
    float Esq = inv_dsh + fmaf(dsh, (1.0f / CUTOFF_SQ_C), -(2.0f / CUTOFF_C));
    float Eq  = (KEHALF_C * qi * qj) * fmaf(sw_off, Esq - Eoq, Eoq);
    float Eod = inv_d * inv_d * inv_d;
    float Esd = inv_dsh * inv_dsh * inv_dsh;
    float Ed  = (KEHALF_C * di * dj) * fmaf(sw_off, Esd - Eod, Eod);
    return Eq + Ed;
}

__device__ __forceinline__ unsigned h2bits(__half2 h) {
    union { __half2 h; unsigned u; } c; c.h = h; return c.u;
}
__device__ __forceinline__ __half2 bits2h(unsigned u) {
    union { unsigned u; __half2 h; } c; c.u = u; return c.h;
}
// half2 atomic add (LDS): HW atomicAdd(__half2*) (ds_pk_add_f16) if available.
template <typename T>
__device__ __forceinline__ auto atom_add_h2(T* p, T v, int)
    -> decltype(atomicAdd(p, v), void()) {
    atomicAdd(p, v);
}
template <typename T>
__device__ __forceinline__ void atom_add_h2(T* p, T v, long) {
    unsigned* u = (unsigned*)p;
    unsigned old = *u, assumed;
    do {
        assumed = old;
        __half2 sum = __hadd2(bits2h(assumed), v);
        old = atomicCAS(u, assumed, h2bits(sum));
    } while (old != assumed);
}

// Fast-exact per-edge radial factors via HW rcp/rsq (errors << fp16 rounding).
// Returns half2{qj*F, dipj*G} bit-pattern. Validity handled by caller.
__device__ __forceinline__ unsigned vw_bits(float d, unsigned hqbits) {
    float inv_d   = __builtin_amdgcn_rcpf(d);
    float dsh2    = fmaf(d, d, 1.0f);
    float inv_dsh = __builtin_amdgcn_rsqf(dsh2);   // 1/sqrt(d^2+1)
    float dsh     = dsh2 * inv_dsh;                // sqrt(d^2+1)
    float x  = d * (1.0f / CUTOFF_SR_C);
    float x3 = x * x * x;
    float sw = fmaf(x3, fmaf(x, fmaf(x, -6.0f, 15.0f), -10.0f), 1.0f);
    float sw_off = (d < CUTOFF_SR_C) ? sw : 0.0f;
    float Foq = inv_d   + fmaf(d,   (1.0f / CUTOFF_SQ_C), -(2.0f / CUTOFF_C));
    float Fsq = inv_dsh + fmaf(dsh, (1.0f / CUTOFF_SQ_C), -(2.0f / CUTOFF_C));
    float F   = fmaf(sw_off, Fsq - Foq, Foq);
    float God = inv_d * inv_d * inv_d;
    float Gsd = inv_dsh * inv_dsh * inv_dsh;
    float G   = fmaf(sw_off, Gsd - God, God);
    float2 q2 = __half22float2(bits2h(hqbits));
    __half2 vw = __floats2half2_rn((KEHALF_C * q2.x) * F, (KEHALF_C * q2.y) * G);
    return h2bits(vw);
}

// Pack {q, dip} -> half2 (4 B / atom), j-side gather table.
__global__ __launch_bounds__(256) void pc_pack_qd_h(
    const float* __restrict__ q,
    const float* __restrict__ dip,
    __half2*     __restrict__ qd,
    int n_atoms)
{
    int a = blockIdx.x * 256 + threadIdx.x;
    if (a < n_atoms) qd[a] = __floats2half2_rn(q[a], dip[a]);
}

// ---------------- FUSED gather+compute+scatter (software-pipelined) ---------
// R8 landed 72us with VGPR=28, VALUBusy 46%, ~21us of unattributed stall:
// the compiler serialized each iteration's stream-load -> gather -> fg ->
// atomic chain. This version explicitly prefetches iteration n+1's three
// stream loads (i/j/d x 2 groups) while processing iteration n, converting
// the per-iteration L2 latency into overlap. VGPR ~52-60 (<=64 keeps duo
// residency: 2 blocks/CU x 16 waves = 8 waves/SIMD).
template <int CH, int BLK>
__global__ __launch_bounds__(BLK) void pc_fused_sc(
    const float*   __restrict__ dist,
    const int*     __restrict__ idx_i,
    const int*     __restrict__ idx_j,
    const __half2* __restrict__ qd,
    __half2*       __restrict__ partial,   // [S][n_atoms] half2 {sumv,sumw}
    int n_edges, int n4, int S, int gps, int n_atoms)
{
    extern __shared__ char smem[];
    __half2* acc2 = (__half2*)smem;                                  // CH

    const int s = blockIdx.x % S;
    const int c = blockIdx.x / S;
    const unsigned base = (unsigned)(c * CH);
    const int lim = min(CH, n_atoms - (int)base);

    // vectorized LDS zero-init (CH % 4 == 0)
    {
        uint4* z4 = (uint4*)acc2;
        const uint4 z = make_uint4(0u, 0u, 0u, 0u);
        for (int i = threadIdx.x; i < CH / 4; i += BLK) z4[i] = z;
    }
    __syncthreads();

    const int4*   i4p = (const int4*)idx_i;
    const int4*   j4p = (const int4*)idx_j;
    const float4* d4p = (const float4*)dist;
    const __half2 hzero = __floats2half2_rn(0.0f, 0.0f);

    const int g0 = s * gps;
    const int g1 = min(g0 + gps, n4);
    int g = g0 + (int)threadIdx.x;

    int4   iA, iB, jA, jB;
    float4 dA, dB;
    bool   hasB = false;

    if (g < g1) {   // prologue: load first 2-group batch
        const int gB  = g + BLK;
        hasB = gB < g1;
        const int gBs = hasB ? gB : g;
        iA = i4p[g];  iB = i4p[gBs];
        jA = j4p[g];  jB = j4p[gBs];
        dA = d4p[g];  dB = d4p[gBs];

        for (;;) {
            // ---- prefetch next batch (overlaps with current processing) ----
            const int  gn   = g + 2 * BLK;
            const bool more = gn < g1;
            int4   niA, niB, njA, njB;
            float4 ndA, ndB;
            bool   nHasB = false;
            if (more) {
                const int gnB  = gn + BLK;
                nHasB = gnB < g1;
                const int gnBs = nHasB ? gnB : gn;
                niA = i4p[gn];  niB = i4p[gnBs];
                njA = j4p[gn];  njB = j4p[gnBs];
                ndA = d4p[gn];  ndB = d4p[gnBs];
            }

            // ---- process current batch ----
            unsigned a0 = (unsigned)iA.x - base;
            unsigned a1 = (unsigned)iA.y - base;
            unsigned a2 = (unsigned)iA.z - base;
            unsigned a3 = (unsigned)iA.w - base;
            unsigned b0 = (unsigned)iB.x - base;
            unsigned b1 = (unsigned)iB.y - base;
            unsigned b2 = (unsigned)iB.z - base;
            unsigned b3 = (unsigned)iB.w - base;

            bool vA0 = (a0 < (unsigned)CH) && (dA.x <= CUTOFF_C);
            bool vA1 = (a1 < (unsigned)CH) && (dA.y <= CUTOFF_C);
            bool vA2 = (a2 < (unsigned)CH) && (dA.z <= CUTOFF_C);
            bool vA3 = (a3 < (unsigned)CH) && (dA.w <= CUTOFF_C);
            bool vB0 = hasB && (b0 < (unsigned)CH) && (dB.x <= CUTOFF_C);
            bool vB1 = hasB && (b1 < (unsigned)CH) && (dB.y <= CUTOFF_C);
            bool vB2 = hasB && (b2 < (unsigned)CH) && (dB.z <= CUTOFF_C);
            bool vB3 = hasB && (b3 < (unsigned)CH) && (dB.w <= CUTOFF_C);

            // masked gathers (only owning chunk + in-cutoff pulls a line)
            __half2 q0 = vA0 ? qd[jA.x] : hzero;
            __half2 q1 = vA1 ? qd[jA.y] : hzero;
            __half2 q2 = vA2 ? qd[jA.z] : hzero;
            __half2 q3 = vA3 ? qd[jA.w] : hzero;
            __half2 q4 = vB0 ? qd[jB.x] : hzero;
            __half2 q5 = vB1 ? qd[jB.y] : hzero;
            __half2 q6 = vB2 ? qd[jB.z] : hzero;
            __half2 q7 = vB3 ? qd[jB.w] : hzero;

            if (vA0) atom_add_h2(&acc2[a0], bits2h(vw_bits(dA.x, h2bits(q0))), 0);
            if (vA1) atom_add_h2(&acc2[a1], bits2h(vw_bits(dA.y, h2bits(q1))), 0);
            if (vA2) atom_add_h2(&acc2[a2], bits2h(vw_bits(dA.z, h2bits(q2))), 0);
            if (vA3) atom_add_h2(&acc2[a3], bits2h(vw_bits(dA.w, h2bits(q3))), 0);
            if (vB0) atom_add_h2(&acc2[b0], bits2h(vw_bits(dB.x, h2bits(q4))), 0);
            if (vB1) atom_add_h2(&acc2[b1], bits2h(vw_bits(dB.y, h2bits(q5))), 0);
            if (vB2) atom_add_h2(&acc2[b2], bits2h(vw_bits(dB.z, h2bits(q6))), 0);
            if (vB3) atom_add_h2(&acc2[b3], bits2h(vw_bits(dB.w, h2bits(q7))), 0);

            if (!more) break;
            // ---- rotate (SSA/phi: no physical copies in steady state) ----
            g = gn;
            iA = niA; iB = niB; jA = njA; jB = njB; dA = ndA; dB = ndB;
            hasB = nHasB;
        }
    }

    if (s == S - 1) {  // scalar tail (n_edges % 4)
        for (int e = (n4 << 2) + (int)threadIdx.x; e < n_edges; e += BLK) {
            unsigned lc = (unsigned)idx_i[e] - base;
            float d = dist[e];
            if (lc < (unsigned)CH && d <= CUTOFF_C) {
                unsigned w = vw_bits(d, h2bits(qd[idx_j[e]]));
                atom_add_h2(&acc2[lc], bits2h(w), 0);
            }
        }
    }

    __syncthreads();
    __half2* row = partial + (size_t)s * n_atoms + (int)base;
    if (((n_atoms & 3) == 0) && (lim & 3) == 0) {
        uint4* r4 = (uint4*)row;
        const uint4* a4 = (const uint4*)acc2;
        for (int i = threadIdx.x; i < lim / 4; i += BLK) r4[i] = a4[i];
    } else {
        for (int i = threadIdx.x; i < lim; i += BLK) row[i] = acc2[i];
    }
}

// out[a] = q[a]*sum_s(v) + dip[a]*sum_s(w) — exact fp32 recombination.
// Requires S % 4 == 0.
__global__ __launch_bounds__(256) void pc_reduce_vw(
    const __half2* __restrict__ partial,   // [S][n_atoms]
    const float*   __restrict__ q,
    const float*   __restrict__ dip,
    float*         __restrict__ out,
    int n_atoms, int S)
{
    __shared__ float2 sh[256];
    int a0   = blockIdx.x * 64;
    int lane = threadIdx.x & 63;
    int w    = threadIdx.x >> 6;
    int a    = a0 + lane;

    float sv = 0.0f, sw = 0.0f;
    if (a < n_atoms) {
        int per = S >> 2;                  // S % 4 == 0
        const __half2* p = partial + a;
        int s = w * per, send = s + per;
        for (; s < send; ++s) {
            float2 t = __half22float2(p[(size_t)s * n_atoms]);
            sv += t.x; sw += t.y;
        }
    }
    sh[threadIdx.x] = make_float2(sv, sw);
    __syncthreads();
    if (w == 0 && a < n_atoms) {
        float2 t0 = sh[lane],       t1 = sh[64 + lane];
        float2 t2 = sh[128 + lane], t3 = sh[192 + lane];
        float fv = (t0.x + t1.x) + (t2.x + t3.x);
        float fw = (t0.y + t1.y) + (t2.y + t3.y);
        out[a] = fmaf(q[a], fv, dip[a] * fw);
    }
}

// Full-precision global-atomic fallback (probe failure / tiny ws).
__global__ __launch_bounds__(256) void pc_dipole_edges_atomic(
    const float* __restrict__ q,
    const float* __restrict__ dip,
    const float* __restrict__ dist,
    const int*   __restrict__ idx_i,
    const int*   __restrict__ idx_j,
    float*       __restrict__ out,
    int n_edges)
{
    int t = blockIdx.x * blockDim.x + threadIdx.x;
    const int stride = gridDim.x * blockDim.x;
    for (int e = t; e < n_edges; e += stride) {
        float d = dist[e];
        if (d > CUTOFF_C) continue;
        int i = idx_i[e], j = idx_j[e];
        atomicAdd(&out[i], edge_energy(d, q[i], q[j], dip[i], dip[j]));
    }
}

static int probe_blocks(const void* f, int blk, size_t lds) {
    hipError_t e1 = hipFuncSetAttribute(
        f, hipFuncAttributeMaxDynamicSharedMemorySize, (int)lds);
    int nb = 0;
    hipError_t e2 = hipOccupancyMaxActiveBlocksPerMultiprocessor(&nb, f, blk, lds);
    if (e1 != hipSuccess || e2 != hipSuccess) return 0;
    return nb;
}

extern "C" void kernel_launch(void* const* d_in, const int* in_sizes, int n_in,
                              void* d_out, int out_size, void* d_ws, size_t ws_size,
                              hipStream_t stream) {
    const float* q     = (const float*)d_in[0];
    const float* dip   = (const float*)d_in[1];
    const float* dist  = (const float*)d_in[2];
    const int*   idx_i = (const int*)d_in[3];
    const int*   idx_j = (const int*)d_in[4];
    float*       out   = (float*)d_out;

    int n_edges = in_sizes[2];
    int n_atoms = out_size;
    int n4      = n_edges >> 2;

    size_t qd_b = ((size_t)n_atoms * sizeof(__half2) + 255) & ~(size_t)255;

    // ---- fused config select: DUO (2 blocks/CU, 32 waves) preferred ----
    size_t lds_duo  = (size_t)CH_DUO  * sizeof(__half2);   //  80000 B
    size_t lds_solo = (size_t)CH_SOLO * sizeof(__half2);   // 160000 B
    int nb_duo  = probe_blocks((const void*)&pc_fused_sc<CH_DUO, BLK1>,
                               BLK1, lds_duo);
    int nb_solo = probe_blocks((const void*)&pc_fused_sc<CH_SOLO, BLK1>,
                               BLK1, lds_solo);

    bool   use_duo = (nb_duo >= 2);
    int    CH  = use_duo ? CH_DUO : CH_SOLO;
    size_t lds = use_duo ? lds_duo : lds_solo;
    int    cap = use_duo ? 512 : 256;           // resident blocks device-wide

    int S = 0, nch = 0;
    bool ok = (use_duo || nb_solo >= 1);
    if (ok && n_atoms > 0 && n4 > 0 && ws_size > qd_b) {
        nch = (n_atoms + CH - 1) / CH;          // 5 (duo) / 3 (solo) @100K
        S = (cap / nch) & ~7;                   // 96 (duo) / 80 (solo)
        size_t avail = ws_size - qd_b;
        int S_fit = (int)(avail / ((size_t)n_atoms * sizeof(__half2))) & ~7;
        if (S_fit < S) S = S_fit;
    }

    if (S >= 8) {
        __half2* qd      = (__half2*)d_ws;
        __half2* partial = (__half2*)((char*)d_ws + qd_b);
        int      gps     = (n4 + S - 1) / S;

        pc_pack_qd_h<<<(n_atoms + 255) / 256, 256, 0, stream>>>(q, dip, qd,
                                                                n_atoms);
        if (use_duo)
            pc_fused_sc<CH_DUO, BLK1>
                <<<S * nch, BLK1, lds, stream>>>(
                    dist, idx_i, idx_j, qd, partial, n_edges, n4, S, gps,
                    n_atoms);
        else
            pc_fused_sc<CH_SOLO, BLK1>
                <<<S * nch, BLK1, lds, stream>>>(
                    dist, idx_i, idx_j, qd, partial, n_edges, n4, S, gps,
                    n_atoms);
        pc_reduce_vw<<<(n_atoms + 63) / 64, 256, 0, stream>>>(
            partial, q, dip, out, n_atoms, S);
        return;
    }

    // ---------- full-precision atomic fallback ----------
    hipMemsetAsync(out, 0, (size_t)n_atoms * sizeof(float), stream);
    int grid = (n_edges + 255) / 256;
    if (grid < 1) grid = 1;
    pc_dipole_edges_atomic<<<grid, 256, 0, stream>>>(
        q, dip, dist, idx_i, idx_j, out, n_edges);
}

// Round 10
// 152.288 us; speedup vs baseline: 1.0141x; 1.0141x over previous
//
#include <hip/hip_runtime.h>
#include <hip/hip_bf16.h>
#include <hip/hip_fp16.h>

// Problem constants (match reference)
#define CUTOFF_C    12.0f
#define CUTOFF_SR_C 2.0f
#define CUTOFF_SQ_C 144.0f
#define KEHALF_C    7.199822675975274f

#define BLK1   1024

// Fused gather+compute+scatter configs (no LUT, exact math):
// DUO : CH=20000 -> 80000 B LDS, 2 blocks/CU, nch=5 @100K, 32M visits.
// SOLO: CH=40000 -> 160000 B LDS, 1 block/CU, nch=3 (fallback if duo probe fails).
#define CH_DUO  20000
#define CH_SOLO 40000

__device__ __forceinline__ float edge_energy(float d, float qi, float qj,
                                             float di, float dj) {
    float inv_d   = __frcp_rn(d);
    float dsh     = __fsqrt_rn(fmaf(d, d, 1.0f));
    float inv_dsh = __frcp_rn(dsh);
    float x  = d * (1.0f / CUTOFF_SR_C);
    float x3 = x * x * x;
    float sw = fmaf(x3, fmaf(x, fmaf(x, -6.0f, 15.0f), -10.0f), 1.0f);
    float sw_off = (d < CUTOFF_SR_C) ? sw : 0.0f;
    float Eoq = inv_d   + fmaf(d,   (1.0f / CUTOFF_SQ_C), -(2.0f / CUTOFF_C));
    float Esq = inv_dsh + fmaf(dsh, (1.0f / CUTOFF_SQ_C), -(2.0f / CUTOFF_C));
    float Eq  = (KEHALF_C * qi * qj) * fmaf(sw_off, Esq - Eoq, Eoq);
    float Eod = inv_d * inv_d * inv_d;
    float Esd = inv_dsh * inv_dsh * inv_dsh;
    float Ed  = (KEHALF_C * di * dj) * fmaf(sw_off, Esd - Eod, Eod);
    return Eq + Ed;
}

__device__ __forceinline__ unsigned h2bits(__half2 h) {
    union { __half2 h; unsigned u; } c; c.h = h; return c.u;
}
__device__ __forceinline__ __half2 bits2h(unsigned u) {
    union { unsigned u; __half2 h; } c; c.u = u; return c.h;
}
// half2 atomic add (LDS): HW atomicAdd(__half2*) (ds_pk_add_f16) if available.
template <typename T>
__device__ __forceinline__ auto atom_add_h2(T* p, T v, int)
    -> decltype(atomicAdd(p, v), void()) {
    atomicAdd(p, v);
}
template <typename T>
__device__ __forceinline__ void atom_add_h2(T* p, T v, long) {
    unsigned* u = (unsigned*)p;
    unsigned old = *u, assumed;
    do {
        assumed = old;
        __half2 sum = __hadd2(bits2h(assumed), v);
        old = atomicCAS(u, assumed, h2bits(sum));
    } while (old != assumed);
}

// Fast-exact per-edge radial factors via HW rcp/rsq (errors << fp16 rounding).
// Returns half2{qj*F, dipj*G} bit-pattern. Validity handled by caller.
__device__ __forceinline__ unsigned vw_bits(float d, unsigned hqbits) {
    float inv_d   = __builtin_amdgcn_rcpf(d);
    float dsh2    = fmaf(d, d, 1.0f);
    float inv_dsh = __builtin_amdgcn_rsqf(dsh2);   // 1/sqrt(d^2+1)
    float dsh     = dsh2 * inv_dsh;                // sqrt(d^2+1)
    float x  = d * (1.0f / CUTOFF_SR_C);
    float x3 = x * x * x;
    float sw = fmaf(x3, fmaf(x, fmaf(x, -6.0f, 15.0f), -10.0f), 1.0f);
    float sw_off = (d < CUTOFF_SR_C) ? sw : 0.0f;
    float Foq = inv_d   + fmaf(d,   (1.0f / CUTOFF_SQ_C), -(2.0f / CUTOFF_C));
    float Fsq = inv_dsh + fmaf(dsh, (1.0f / CUTOFF_SQ_C), -(2.0f / CUTOFF_C));
    float F   = fmaf(sw_off, Fsq - Foq, Foq);
    float God = inv_d * inv_d * inv_d;
    float Gsd = inv_dsh * inv_dsh * inv_dsh;
    float G   = fmaf(sw_off, Gsd - God, God);
    float2 q2 = __half22float2(bits2h(hqbits));
    __half2 vw = __floats2half2_rn((KEHALF_C * q2.x) * F, (KEHALF_C * q2.y) * G);
    return h2bits(vw);
}

// Pack {q, dip} -> half2 (4 B / atom), j-side gather table.
__global__ __launch_bounds__(256) void pc_pack_qd_h(
    const float* __restrict__ q,
    const float* __restrict__ dip,
    __half2*     __restrict__ qd,
    int n_atoms)
{
    int a = blockIdx.x * 256 + threadIdx.x;
    if (a < n_atoms) qd[a] = __floats2half2_rn(q[a], dip[a]);
}

// ---------------- FUSED gather+compute+scatter (exact math, no LUT) ---------
// Best-measured form (R8: 152.5us end-to-end, fused 72us). nch=5 (CH=20000),
// exact rcp/rsq math (no LUT LDS reads), 2-group unroll, masked gathers
// (only owning chunk + in-cutoff lanes pull a line -> 1x gather traffic).
// R9's explicit software pipeline was compiler-defeated (VGPR stayed 32,
// slight regression) - reverted. Block b: s = b % S (edge slice),
// c = b / S (atom chunk). S % 8 == 0 keeps same-slice blocks on one XCD.
template <int CH, int BLK>
__global__ __launch_bounds__(BLK) void pc_fused_sc(
    const float*   __restrict__ dist,
    const int*     __restrict__ idx_i,
    const int*     __restrict__ idx_j,
    const __half2* __restrict__ qd,
    __half2*       __restrict__ partial,   // [S][n_atoms] half2 {sumv,sumw}
    int n_edges, int n4, int S, int gps, int n_atoms)
{
    extern __shared__ char smem[];
    __half2* acc2 = (__half2*)smem;                                  // CH

    const int s = blockIdx.x % S;
    const int c = blockIdx.x / S;
    const unsigned base = (unsigned)(c * CH);
    const int lim = min(CH, n_atoms - (int)base);

    // vectorized LDS zero-init (CH % 4 == 0)
    {
        uint4* z4 = (uint4*)acc2;
        const uint4 z = make_uint4(0u, 0u, 0u, 0u);
        for (int i = threadIdx.x; i < CH / 4; i += BLK) z4[i] = z;
    }
    __syncthreads();

    const int4*   i4p = (const int4*)idx_i;
    const int4*   j4p = (const int4*)idx_j;
    const float4* d4p = (const float4*)dist;
    const __half2 hzero = __floats2half2_rn(0.0f, 0.0f);

    const int g0 = s * gps;
    const int g1 = min(g0 + gps, n4);
    for (int g = g0 + (int)threadIdx.x; g < g1; g += 2 * BLK) {
        const int  gB   = g + BLK;
        const bool hasB = gB < g1;
        const int  gBs  = hasB ? gB : g;

        int4   iA = i4p[g];
        int4   iB = i4p[gBs];
        int4   jA = j4p[g];
        int4   jB = j4p[gBs];
        float4 dA = d4p[g];
        float4 dB = d4p[gBs];

        unsigned a0 = (unsigned)iA.x - base;
        unsigned a1 = (unsigned)iA.y - base;
        unsigned a2 = (unsigned)iA.z - base;
        unsigned a3 = (unsigned)iA.w - base;
        unsigned b0 = (unsigned)iB.x - base;
        unsigned b1 = (unsigned)iB.y - base;
        unsigned b2 = (unsigned)iB.z - base;
        unsigned b3 = (unsigned)iB.w - base;

        bool vA0 = (a0 < (unsigned)CH) && (dA.x <= CUTOFF_C);
        bool vA1 = (a1 < (unsigned)CH) && (dA.y <= CUTOFF_C);
        bool vA2 = (a2 < (unsigned)CH) && (dA.z <= CUTOFF_C);
        bool vA3 = (a3 < (unsigned)CH) && (dA.w <= CUTOFF_C);
        bool vB0 = hasB && (b0 < (unsigned)CH) && (dB.x <= CUTOFF_C);
        bool vB1 = hasB && (b1 < (unsigned)CH) && (dB.y <= CUTOFF_C);
        bool vB2 = hasB && (b2 < (unsigned)CH) && (dB.z <= CUTOFF_C);
        bool vB3 = hasB && (b3 < (unsigned)CH) && (dB.w <= CUTOFF_C);

        // masked gathers (only owning chunk + in-cutoff pulls a line)
        __half2 q0 = vA0 ? qd[jA.x] : hzero;
        __half2 q1 = vA1 ? qd[jA.y] : hzero;
        __half2 q2 = vA2 ? qd[jA.z] : hzero;
        __half2 q3 = vA3 ? qd[jA.w] : hzero;
        __half2 q4 = vB0 ? qd[jB.x] : hzero;
        __half2 q5 = vB1 ? qd[jB.y] : hzero;
        __half2 q6 = vB2 ? qd[jB.z] : hzero;
        __half2 q7 = vB3 ? qd[jB.w] : hzero;

        if (vA0) atom_add_h2(&acc2[a0], bits2h(vw_bits(dA.x, h2bits(q0))), 0);
        if (vA1) atom_add_h2(&acc2[a1], bits2h(vw_bits(dA.y, h2bits(q1))), 0);
        if (vA2) atom_add_h2(&acc2[a2], bits2h(vw_bits(dA.z, h2bits(q2))), 0);
        if (vA3) atom_add_h2(&acc2[a3], bits2h(vw_bits(dA.w, h2bits(q3))), 0);
        if (vB0) atom_add_h2(&acc2[b0], bits2h(vw_bits(dB.x, h2bits(q4))), 0);
        if (vB1) atom_add_h2(&acc2[b1], bits2h(vw_bits(dB.y, h2bits(q5))), 0);
        if (vB2) atom_add_h2(&acc2[b2], bits2h(vw_bits(dB.z, h2bits(q6))), 0);
        if (vB3) atom_add_h2(&acc2[b3], bits2h(vw_bits(dB.w, h2bits(q7))), 0);
    }

    if (s == S - 1) {  // scalar tail (n_edges % 4)
        for (int e = (n4 << 2) + (int)threadIdx.x; e < n_edges; e += BLK) {
            unsigned lc = (unsigned)idx_i[e] - base;
            float d = dist[e];
            if (lc < (unsigned)CH && d <= CUTOFF_C) {
                unsigned w = vw_bits(d, h2bits(qd[idx_j[e]]));
                atom_add_h2(&acc2[lc], bits2h(w), 0);
            }
        }
    }

    __syncthreads();
    __half2* row = partial + (size_t)s * n_atoms + (int)base;
    if (((n_atoms & 3) == 0) && (lim & 3) == 0) {
        uint4* r4 = (uint4*)row;
        const uint4* a4 = (const uint4*)acc2;
        for (int i = threadIdx.x; i < lim / 4; i += BLK) r4[i] = a4[i];
    } else {
        for (int i = threadIdx.x; i < lim; i += BLK) row[i] = acc2[i];
    }
}

// out[a] = q[a]*sum_s(v) + dip[a]*sum_s(w) — exact fp32 recombination.
// Requires S % 4 == 0.
__global__ __launch_bounds__(256) void pc_reduce_vw(
    const __half2* __restrict__ partial,   // [S][n_atoms]
    const float*   __restrict__ q,
    const float*   __restrict__ dip,
    float*         __restrict__ out,
    int n_atoms, int S)
{
    __shared__ float2 sh[256];
    int a0   = blockIdx.x * 64;
    int lane = threadIdx.x & 63;
    int w    = threadIdx.x >> 6;
    int a    = a0 + lane;

    float sv = 0.0f, sw = 0.0f;
    if (a < n_atoms) {
        int per = S >> 2;                  // S % 4 == 0
        const __half2* p = partial + a;
        int s = w * per, send = s + per;
        for (; s < send; ++s) {
            float2 t = __half22float2(p[(size_t)s * n_atoms]);
            sv += t.x; sw += t.y;
        }
    }
    sh[threadIdx.x] = make_float2(sv, sw);
    __syncthreads();
    if (w == 0 && a < n_atoms) {
        float2 t0 = sh[lane],       t1 = sh[64 + lane];
        float2 t2 = sh[128 + lane], t3 = sh[192 + lane];
        float fv = (t0.x + t1.x) + (t2.x + t3.x);
        float fw = (t0.y + t1.y) + (t2.y + t3.y);
        out[a] = fmaf(q[a], fv, dip[a] * fw);
    }
}

// Full-precision global-atomic fallback (probe failure / tiny ws).
__global__ __launch_bounds__(256) void pc_dipole_edges_atomic(
    const float* __restrict__ q,
    const float* __restrict__ dip,
    const float* __restrict__ dist,
    const int*   __restrict__ idx_i,
    const int*   __restrict__ idx_j,
    float*       __restrict__ out,
    int n_edges)
{
    int t = blockIdx.x * blockDim.x + threadIdx.x;
    const int stride = gridDim.x * blockDim.x;
    for (int e = t; e < n_edges; e += stride) {
        float d = dist[e];
        if (d > CUTOFF_C) continue;
        int i = idx_i[e], j = idx_j[e];
        atomicAdd(&out[i], edge_energy(d, q[i], q[j], dip[i], dip[j]));
    }
}

static int probe_blocks(const void* f, int blk, size_t lds) {
    hipError_t e1 = hipFuncSetAttribute(
        f, hipFuncAttributeMaxDynamicSharedMemorySize, (int)lds);
    int nb = 0;
    hipError_t e2 = hipOccupancyMaxActiveBlocksPerMultiprocessor(&nb, f, blk, lds);
    if (e1 != hipSuccess || e2 != hipSuccess) return 0;
    return nb;
}

extern "C" void kernel_launch(void* const* d_in, const int* in_sizes, int n_in,
                              void* d_out, int out_size, void* d_ws, size_t ws_size,
                              hipStream_t stream) {
    const float* q     = (const float*)d_in[0];
    const float* dip   = (const float*)d_in[1];
    const float* dist  = (const float*)d_in[2];
    const int*   idx_i = (const int*)d_in[3];
    const int*   idx_j = (const int*)d_in[4];
    float*       out   = (float*)d_out;

    int n_edges = in_sizes[2];
    int n_atoms = out_size;
    int n4      = n_edges >> 2;

    size_t qd_b = ((size_t)n_atoms * sizeof(__half2) + 255) & ~(size_t)255;

    // ---- fused config select: DUO (2 blocks/CU, 32 waves) preferred ----
    size_t lds_duo  = (size_t)CH_DUO  * sizeof(__half2);   //  80000 B
    size_t lds_solo = (size_t)CH_SOLO * sizeof(__half2);   // 160000 B
    int nb_duo  = probe_blocks((const void*)&pc_fused_sc<CH_DUO, BLK1>,
                               BLK1, lds_duo);
    int nb_solo = probe_blocks((const void*)&pc_fused_sc<CH_SOLO, BLK1>,
                               BLK1, lds_solo);

    bool   use_duo = (nb_duo >= 2);
    int    CH  = use_duo ? CH_DUO : CH_SOLO;
    size_t lds = use_duo ? lds_duo : lds_solo;
    int    cap = use_duo ? 512 : 256;           // resident blocks device-wide

    int S = 0, nch = 0;
    bool ok = (use_duo || nb_solo >= 1);
    if (ok && n_atoms > 0 && n4 > 0 && ws_size > qd_b) {
        nch = (n_atoms + CH - 1) / CH;          // 5 (duo) / 3 (solo) @100K
        S = (cap / nch) & ~7;                   // 96 (duo) / 80 (solo)
        size_t avail = ws_size - qd_b;
        int S_fit = (int)(avail / ((size_t)n_atoms * sizeof(__half2))) & ~7;
        if (S_fit < S) S = S_fit;
    }

    if (S >= 8) {
        __half2* qd      = (__half2*)d_ws;
        __half2* partial = (__half2*)((char*)d_ws + qd_b);
        int      gps     = (n4 + S - 1) / S;

        pc_pack_qd_h<<<(n_atoms + 255) / 256, 256, 0, stream>>>(q, dip, qd,
                                                                n_atoms);
        if (use_duo)
            pc_fused_sc<CH_DUO, BLK1>
                <<<S * nch, BLK1, lds, stream>>>(
                    dist, idx_i, idx_j, qd, partial, n_edges, n4, S, gps,
                    n_atoms);
        else
            pc_fused_sc<CH_SOLO, BLK1>
                <<<S * nch, BLK1, lds, stream>>>(
                    dist, idx_i, idx_j, qd, partial, n_edges, n4, S, gps,
                    n_atoms);
        pc_reduce_vw<<<(n_atoms + 63) / 64, 256, 0, stream>>>(
            partial, q, dip, out, n_atoms, S);
        return;
    }

    // ---------- full-precision atomic fallback ----------
    hipMemsetAsync(out, 0, (size_t)n_atoms * sizeof(float), stream);
    int grid = (n_edges + 255) / 256;
    if (grid < 1) grid = 1;
    pc_dipole_edges_atomic<<<grid, 256, 0, stream>>>(
        q, dip, dist, idx_i, idx_j, out, n_edges);
}